// Round 5
// baseline (107.978 us; speedup 1.0000x reference)
//
#include <hip/hip_runtime.h>
#include <hip/hip_bf16.h>

// BATCH=512, INPUT_SIZE=64, ALPHA_DIM=64
// out[b,:] = log( M_0 M_1 ... M_62 p ),  M_t = sigma_v(theta_t) col-scaled by
// softmax(u_t); v per (b,t) from ballot mask of x; p from theta_63[:,0].
//
// quad_kernel: all 248 group-product matrices (15 quads x 16 variants + 8
//   triple variants), bf16, stored row-major for EVEN group positions (future
//   MFMA A-operand) and col-major for ODD positions (future B-operand).
// tree_kernel: 1 block/batch, 8 waves. Leaf: H_w = G_{2w} G_{2w+1} from
//   global frags. Levels 2-4: balanced tree through XOR-swizzled LDS role
//   buffers. Final: matvec with p on wave 0, single log. Depth 5, high TLP.

#define NSTEP 63

typedef __attribute__((ext_vector_type(8)))  short short8;
typedef __attribute__((ext_vector_type(16))) float f32x16;

union U8 { short8 v; unsigned u[4]; unsigned short s[8]; };

static __device__ __forceinline__ unsigned short bf16b(float f) {
  union { __hip_bfloat16 h; unsigned short u; } cv;
  cv.h = __float2bfloat16(f);
  return cv.u;
}
static __device__ __forceinline__ unsigned pack2(float a, float b) {
  return (unsigned)bf16b(a) | ((unsigned)bf16b(b) << 16);
}

// ---------------- precompute: one wave per (group, variant) product ----------
__global__ __launch_bounds__(64) void quad_kernel(
    const float* __restrict__ theta, const float* __restrict__ ulpa,
    unsigned short* __restrict__ MqB) {
  __shared__ __align__(16) unsigned short Elds[4 * 4096];
  __shared__ float paL[4][64];

  int bid = blockIdx.x;
  int lane = threadIdx.x, lo = lane & 31, hi = lane >> 5;
  int v, nt, t0, g;
  if (bid < 240) { v = bid & 15; nt = 4; g = bid >> 4; t0 = 4 * g; }
  else           { v = bid - 240; nt = 3; g = 15; t0 = 60; }

  for (int i = 0; i < nt; ++i) {
    float uu = ulpa[(t0 + i) * 64 + lane];
    float m = uu;
    #pragma unroll
    for (int o = 32; o >= 1; o >>= 1) m = fmaxf(m, __shfl_xor(m, o));
    float e = __expf(uu - m);
    float s = e;
    #pragma unroll
    for (int o = 32; o >= 1; o >>= 1) s += __shfl_xor(s, o);
    paL[i][lane] = e / s;
  }

  // E_i[row][col] = sigma_{b_i}(theta[row][col]) * pa[col], bf16, XOR-swizzled
  for (int i = 0; i < nt; ++i) {
    int vb = (v >> i) & 1;
    const float4* th4 = (const float4*)(theta + (t0 + i) * 4096);
    #pragma unroll
    for (int it = 0; it < 16; ++it) {
      int q = it * 64 + lane;
      int row = q >> 4, c = q & 15;
      float4 tv = th4[q];
      float4 pv = *(const float4*)&paL[i][4 * c];
      float s0 = 1.0f / (1.0f + __expf(-tv.x));
      float s1 = 1.0f / (1.0f + __expf(-tv.y));
      float s2 = 1.0f / (1.0f + __expf(-tv.z));
      float s3 = 1.0f / (1.0f + __expf(-tv.w));
      if (!vb) { s0 = 1.0f - s0; s1 = 1.0f - s1; s2 = 1.0f - s2; s3 = 1.0f - s3; }
      unsigned w0 = pack2(s0 * pv.x, s1 * pv.y);
      unsigned w1 = pack2(s2 * pv.z, s3 * pv.w);
      unsigned byteoff = (unsigned)(i * 8192) +
          (((unsigned)(row * 128 + 8 * c)) ^ ((unsigned)(row & 7) << 4));
      *reinterpret_cast<uint2*>(reinterpret_cast<char*>(Elds) + byteoff) =
          make_uint2(w0, w1);
    }
  }

  // first B-frags = E_{nt-1}
  U8 Bf[4][2];
  {
    int ib = nt - 1;
    #pragma unroll
    for (int kc = 0; kc < 4; ++kc)
      #pragma unroll
      for (int j = 0; j < 2; ++j)
        #pragma unroll
        for (int e = 0; e < 8; ++e) {
          int krow = 16 * kc + 8 * hi + e;
          unsigned byteoff = (unsigned)(ib * 8192) +
              (((unsigned)(krow * 128 + (32 * j + lo) * 2)) ^
               ((unsigned)(krow & 7) << 4));
          Bf[kc][j].s[e] =
              *reinterpret_cast<const unsigned short*>(
                  reinterpret_cast<const char*>(Elds) + byteoff);
        }
  }

  f32x16 C[2][2];
  for (int im = nt - 2; im >= 0; --im) {
    short8 A[4][2];
    #pragma unroll
    for (int kc = 0; kc < 4; ++kc)
      #pragma unroll
      for (int ti = 0; ti < 2; ++ti) {
        int arow = 32 * ti + lo;
        unsigned byteoff = (unsigned)(im * 8192) +
            (((unsigned)(arow * 128 + (16 * kc + 8 * hi) * 2)) ^
             ((unsigned)(arow & 7) << 4));
        A[kc][ti] = *reinterpret_cast<const short8*>(
            reinterpret_cast<const char*>(Elds) + byteoff);
      }

    #pragma unroll
    for (int ti = 0; ti < 2; ++ti)
      #pragma unroll
      for (int j = 0; j < 2; ++j)
        #pragma unroll
        for (int r = 0; r < 16; ++r) C[ti][j][r] = 0.0f;

    #pragma unroll
    for (int kc = 0; kc < 4; ++kc)
      #pragma unroll
      for (int j = 0; j < 2; ++j)
        #pragma unroll
        for (int ti = 0; ti < 2; ++ti)
          C[ti][j] = __builtin_amdgcn_mfma_f32_32x32x16_bf16(
              A[kc][ti], Bf[kc][j].v, C[ti][j], 0, 0, 0);

    if (im > 0) {
      // rebuild B-frags from C (validated lane^32 parity exchange)
      #pragma unroll
      for (int kc = 0; kc < 4; ++kc) {
        int Me = 2 * kc, Mo = 2 * kc + 1;
        int tie = Me >> 2, me = Me & 3;
        int tio = Mo >> 2, mo = Mo & 3;
        #pragma unroll
        for (int j = 0; j < 2; ++j) {
          unsigned pe0 = pack2(C[tie][j][4 * me + 0], C[tie][j][4 * me + 1]);
          unsigned pe1 = pack2(C[tie][j][4 * me + 2], C[tie][j][4 * me + 3]);
          unsigned po0 = pack2(C[tio][j][4 * mo + 0], C[tio][j][4 * mo + 1]);
          unsigned po1 = pack2(C[tio][j][4 * mo + 2], C[tio][j][4 * mo + 3]);
          unsigned s0 = hi ? pe0 : po0;
          unsigned s1 = hi ? pe1 : po1;
          unsigned r0 = (unsigned)__shfl_xor((int)s0, 32);
          unsigned r1 = (unsigned)__shfl_xor((int)s1, 32);
          Bf[kc][j].u[0] = hi ? r0 : pe0;
          Bf[kc][j].u[1] = hi ? r1 : pe1;
          Bf[kc][j].u[2] = hi ? po0 : r0;
          Bf[kc][j].u[3] = hi ? po1 : r1;
        }
      }
    }
  }

  // store bf16, role by group-position parity
  unsigned short* outp = MqB + (size_t)bid * 4096;
  if ((g & 1) == 0) {
    // A-role: row-major M[m][n]
    #pragma unroll
    for (int ti = 0; ti < 2; ++ti)
      #pragma unroll
      for (int j = 0; j < 2; ++j)
        #pragma unroll
        for (int r = 0; r < 16; ++r) {
          int m = 32 * ti + (r & 3) + 8 * (r >> 2) + 4 * hi;
          int n = 32 * j + lo;
          outp[m * 64 + n] = bf16b(C[ti][j][r]);
        }
  } else {
    // B-role: col-major Mt[n][m], 4 consecutive m packed per store
    #pragma unroll
    for (int ti = 0; ti < 2; ++ti)
      #pragma unroll
      for (int j = 0; j < 2; ++j)
        #pragma unroll
        for (int rq = 0; rq < 4; ++rq) {
          int n = 32 * j + lo;
          int mb = 32 * ti + 8 * rq + 4 * hi;
          uint2 wv = make_uint2(
              pack2(C[ti][j][4 * rq + 0], C[ti][j][4 * rq + 1]),
              pack2(C[ti][j][4 * rq + 2], C[ti][j][4 * rq + 3]));
          *reinterpret_cast<uint2*>(&outp[n * 64 + mb]) = wv;
        }
  }
}

// ---------------- tree kernel helpers ----------------
static __device__ __forceinline__ void mm64(const short8 A[4][2],
                                            const short8 B[4][2],
                                            f32x16 C[2][2]) {
  #pragma unroll
  for (int ti = 0; ti < 2; ++ti)
    #pragma unroll
    for (int j = 0; j < 2; ++j)
      #pragma unroll
      for (int r = 0; r < 16; ++r) C[ti][j][r] = 0.0f;
  #pragma unroll
  for (int kc = 0; kc < 4; ++kc)
    #pragma unroll
    for (int j = 0; j < 2; ++j)
      #pragma unroll
      for (int ti = 0; ti < 2; ++ti)
        C[ti][j] = __builtin_amdgcn_mfma_f32_32x32x16_bf16(
            A[kc][ti], B[kc][j], C[ti][j], 0, 0, 0);
}

// store C into LDS role buffer (bf16, XOR-swizzled: byte ^= (row&7)<<4)
static __device__ __forceinline__ void store_role(const f32x16 C[2][2],
                                                  char* base, int role,
                                                  int lo, int hi) {
  if (role == 0) {
    #pragma unroll
    for (int ti = 0; ti < 2; ++ti)
      #pragma unroll
      for (int j = 0; j < 2; ++j)
        #pragma unroll
        for (int r = 0; r < 16; ++r) {
          int m = 32 * ti + (r & 3) + 8 * (r >> 2) + 4 * hi;
          int n = 32 * j + lo;
          unsigned byteoff =
              ((unsigned)(m * 128 + n * 2)) ^ ((unsigned)(m & 7) << 4);
          *reinterpret_cast<unsigned short*>(base + byteoff) =
              bf16b(C[ti][j][r]);
        }
  } else {
    #pragma unroll
    for (int ti = 0; ti < 2; ++ti)
      #pragma unroll
      for (int j = 0; j < 2; ++j)
        #pragma unroll
        for (int rq = 0; rq < 4; ++rq) {
          int n = 32 * j + lo;
          int mb = 32 * ti + 8 * rq + 4 * hi;
          unsigned byteoff =
              ((unsigned)(n * 128 + mb * 2)) ^ ((unsigned)(n & 7) << 4);
          uint2 wv = make_uint2(
              pack2(C[ti][j][4 * rq + 0], C[ti][j][4 * rq + 1]),
              pack2(C[ti][j][4 * rq + 2], C[ti][j][4 * rq + 3]));
          *reinterpret_cast<uint2*>(base + byteoff) = wv;
        }
  }
}

static __device__ __forceinline__ void load_frags_lds(short8 A[4][2],
                                                      const char* baseA,
                                                      short8 B[4][2],
                                                      const char* baseB,
                                                      int lo, int hi) {
  #pragma unroll
  for (int kc = 0; kc < 4; ++kc) {
    #pragma unroll
    for (int ti = 0; ti < 2; ++ti) {
      int m = 32 * ti + lo;
      unsigned byteoff = ((unsigned)(m * 128 + (16 * kc + 8 * hi) * 2)) ^
                         ((unsigned)(m & 7) << 4);
      A[kc][ti] = *reinterpret_cast<const short8*>(baseA + byteoff);
    }
    #pragma unroll
    for (int j = 0; j < 2; ++j) {
      int n = 32 * j + lo;
      unsigned byteoff = ((unsigned)(n * 128 + (16 * kc + 8 * hi) * 2)) ^
                         ((unsigned)(n & 7) << 4);
      B[kc][j] = *reinterpret_cast<const short8*>(baseB + byteoff);
    }
  }
}

// ---------------- tree: 1 block/batch, 8 waves, depth-5 ----------------
__global__ __launch_bounds__(512, 2) void tree_kernel(
    const float* __restrict__ x, const float* __restrict__ theta,
    const unsigned short* __restrict__ MqB, float* __restrict__ out) {
  __shared__ __align__(16) char Lsh[8 * 8192];   // 8 role buffers, 64 KB

  int b = blockIdx.x, tid = threadIdx.x;
  int w = tid >> 6, lane = tid & 63, lo = lane & 31, hi = lane >> 5;

  unsigned long long mask = __ballot(x[b * 64 + lane] != 0.0f);

#define GIDX(g) ((g) < 15 ? (g) * 16 + (int)((mask >> (4 * (g))) & 15ull) \
                          : 240 + (int)((mask >> 60) & 7ull))

  short8 A[4][2], B[4][2];
  f32x16 C[2][2];

  // ---- leaf: H_w = G_{2w} (row-major) x G_{2w+1} (col-major), from global
  {
    const unsigned short* GA = MqB + (size_t)GIDX(2 * w) * 4096;
    const unsigned short* GB = MqB + (size_t)GIDX(2 * w + 1) * 4096;
    #pragma unroll
    for (int kc = 0; kc < 4; ++kc) {
      #pragma unroll
      for (int ti = 0; ti < 2; ++ti)
        A[kc][ti] = *reinterpret_cast<const short8*>(
            &GA[(32 * ti + lo) * 64 + 16 * kc + 8 * hi]);
      #pragma unroll
      for (int j = 0; j < 2; ++j)
        B[kc][j] = *reinterpret_cast<const short8*>(
            &GB[(32 * j + lo) * 64 + 16 * kc + 8 * hi]);
    }
    mm64(A, B, C);
    store_role(C, Lsh + w * 8192, w & 1, lo, hi);
  }
  __syncthreads();                                   // B1

  // ---- level 2: waves 0..3
  if (w < 4)
    load_frags_lds(A, Lsh + (2 * w) * 8192, B, Lsh + (2 * w + 1) * 8192, lo, hi);
  __syncthreads();                                   // B2
  if (w < 4) {
    mm64(A, B, C);
    store_role(C, Lsh + w * 8192, w & 1, lo, hi);
  }
  __syncthreads();                                   // B3

  // ---- level 3: waves 0..1
  if (w < 2)
    load_frags_lds(A, Lsh + (2 * w) * 8192, B, Lsh + (2 * w + 1) * 8192, lo, hi);
  __syncthreads();                                   // B4
  if (w < 2) {
    mm64(A, B, C);
    store_role(C, Lsh + w * 8192, w & 1, lo, hi);
  }
  __syncthreads();                                   // B5

  // ---- level 4 + matvec + log: wave 0
  if (w == 0) {
    load_frags_lds(A, Lsh + 0, B, Lsh + 8192, lo, hi);
    mm64(A, B, C);      // C = L = G_0 ... G_15 (fp32 regs)

    // scatter L into chain layout (fp32) over buffers 0-1; u at buffer 2
    float* lf = reinterpret_cast<float*>(Lsh);
    #pragma unroll
    for (int ti = 0; ti < 2; ++ti)
      #pragma unroll
      for (int j = 0; j < 2; ++j)
        #pragma unroll
        for (int r = 0; r < 16; ++r) {
          int m = 32 * ti + (r & 3) + 8 * (r >> 2) + 4 * hi;
          int n = 32 * j + lo;
          lf[(n >> 2) * 256 + m * 4 + (n & 3)] = C[ti][j][r];
        }

    float th = theta[63 * 4096 + lane * 64];
    float sg = 1.0f / (1.0f + __expf(-th));
    float* u = lf + 4096;
    u[lane] = ((mask >> 63) & 1ull) ? sg : (1.0f - sg);

    const float4* Qm4 = reinterpret_cast<const float4*>(lf);
    float s0 = 0.f, s1 = 0.f, s2 = 0.f, s3 = 0.f;
    #pragma unroll
    for (int gq = 0; gq < 16; gq += 4) {
      float4 q0 = Qm4[(gq + 0) * 64 + lane];
      float4 q1 = Qm4[(gq + 1) * 64 + lane];
      float4 q2 = Qm4[(gq + 2) * 64 + lane];
      float4 q3 = Qm4[(gq + 3) * 64 + lane];
      float4 u0 = *(const float4*)&u[(gq + 0) * 4];
      float4 u1 = *(const float4*)&u[(gq + 1) * 4];
      float4 u2 = *(const float4*)&u[(gq + 2) * 4];
      float4 u3 = *(const float4*)&u[(gq + 3) * 4];
      s0 = fmaf(q0.x, u0.x, s0); s0 = fmaf(q0.y, u0.y, s0);
      s0 = fmaf(q0.z, u0.z, s0); s0 = fmaf(q0.w, u0.w, s0);
      s1 = fmaf(q1.x, u1.x, s1); s1 = fmaf(q1.y, u1.y, s1);
      s1 = fmaf(q1.z, u1.z, s1); s1 = fmaf(q1.w, u1.w, s1);
      s2 = fmaf(q2.x, u2.x, s2); s2 = fmaf(q2.y, u2.y, s2);
      s2 = fmaf(q2.z, u2.z, s2); s2 = fmaf(q2.w, u2.w, s2);
      s3 = fmaf(q3.x, u3.x, s3); s3 = fmaf(q3.y, u3.y, s3);
      s3 = fmaf(q3.z, u3.z, s3); s3 = fmaf(q3.w, u3.w, s3);
    }
    float s = (s0 + s1) + (s2 + s3);
    out[b * 64 + lane] = logf(s);
  }
#undef GIDX
}

extern "C" void kernel_launch(void* const* d_in, const int* in_sizes, int n_in,
                              void* d_out, int out_size, void* d_ws, size_t ws_size,
                              hipStream_t stream) {
  const float* x     = (const float*)d_in[0];  // (512, 64)
  const float* theta = (const float*)d_in[1];  // (1, 64, 64, 64)
  const float* ulpa  = (const float*)d_in[2];  // (1, 63, 1, 64)
  float* out = (float*)d_out;                  // (512, 64, 1)

  unsigned short* MqB = (unsigned short*)d_ws; // 248 * 4096 bf16 (~2 MB)

  hipLaunchKernelGGL(quad_kernel, dim3(248), dim3(64), 0, stream,
                     theta, ulpa, MqB);
  hipLaunchKernelGGL(tree_kernel, dim3(512), dim3(512), 0, stream,
                     x, theta, MqB, out);
}

// Round 6
// 85.873 us; speedup vs baseline: 1.2574x; 1.2574x over previous
//
#include <hip/hip_runtime.h>
#include <hip/hip_bf16.h>

// BATCH=512, INPUT_SIZE=64, ALPHA_DIM=64
// out[b,:] = log( M_0 ... M_62 p ).  Pipeline:
//  e_kernel:   E[t][v] = sigma_v(theta_t) col-scaled by softmax(u_t), bf16,
//              stored dual-layout: EA row-major, EB col-major. One expf per
//              element serves both variants. 63 blocks x 256 thr.
//  quad_kernel: all 248 group products (15 quads x 16 v + 8 triple v) as
//              PT = (E...E)^T via transpose-operand aliasing:
//                bytes(EB) as A-frag == E^T ;  bytes(EA) as B-frag == E^T
//              depth-2 MFMA, one LDS role-0 round trip, lane^32 B-rebuild.
//              Dual-role store of PT (roles swapped => A/B-role of P).
//  tree_kernel: 1 block/batch, 8 waves, balanced depth-5 tree (R5, validated).

#define NSTEP 63

typedef __attribute__((ext_vector_type(8)))  short short8;
typedef __attribute__((ext_vector_type(16))) float f32x16;

union U8 { short8 v; unsigned u[4]; unsigned short s[8]; };

static __device__ __forceinline__ unsigned short bf16b(float f) {
  union { __hip_bfloat16 h; unsigned short u; } cv;
  cv.h = __float2bfloat16(f);
  return cv.u;
}
static __device__ __forceinline__ unsigned pack2(float a, float b) {
  return (unsigned)bf16b(a) | ((unsigned)bf16b(b) << 16);
}

// ---------------- e_kernel: E tables, dual layout ----------------
// EA[(t*2+v)*4096 + m*64 + n] = E_v[m][n]   (row-major)
// EB[(t*2+v)*4096 + n*64 + m] = E_v[m][n]   (col-major)
__global__ __launch_bounds__(256) void e_kernel(
    const float* __restrict__ theta, const float* __restrict__ ulpa,
    unsigned short* __restrict__ EA, unsigned short* __restrict__ EB) {
  int t = blockIdx.x;          // 0..62
  int tid = threadIdx.x;
  __shared__ float sig[64][65];
  __shared__ float pa[64];

  if (tid < 64) {
    float u = ulpa[t * 64 + tid];
    float m = u;
    #pragma unroll
    for (int o = 32; o >= 1; o >>= 1) m = fmaxf(m, __shfl_xor(m, o));
    float e = __expf(u - m);
    float s = e;
    #pragma unroll
    for (int o = 32; o >= 1; o >>= 1) s += __shfl_xor(s, o);
    pa[tid] = e / s;
  }

  const float4* th4 = (const float4*)(theta + t * 4096);
  #pragma unroll
  for (int k = 0; k < 4; ++k) {
    int i = tid + k * 256;          // float4 idx
    float4 v = th4[i];
    int m = i >> 4, n0 = (i & 15) * 4;
    sig[m][n0 + 0] = 1.0f / (1.0f + __expf(-v.x));
    sig[m][n0 + 1] = 1.0f / (1.0f + __expf(-v.y));
    sig[m][n0 + 2] = 1.0f / (1.0f + __expf(-v.z));
    sig[m][n0 + 3] = 1.0f / (1.0f + __expf(-v.w));
  }
  __syncthreads();

  unsigned short* EA0 = EA + (size_t)(t * 2 + 0) * 4096;
  unsigned short* EA1 = EA + (size_t)(t * 2 + 1) * 4096;
  unsigned short* EB0 = EB + (size_t)(t * 2 + 0) * 4096;
  unsigned short* EB1 = EB + (size_t)(t * 2 + 1) * 4096;

  #pragma unroll
  for (int k = 0; k < 4; ++k) {
    int i = tid + k * 256;
    int m = i >> 4, n0 = (i & 15) * 4;
    float p0 = pa[n0], p1 = pa[n0 + 1], p2 = pa[n0 + 2], p3 = pa[n0 + 3];
    float s0 = sig[m][n0], s1 = sig[m][n0 + 1];
    float s2 = sig[m][n0 + 2], s3 = sig[m][n0 + 3];
    *reinterpret_cast<uint2*>(&EA1[m * 64 + n0]) =
        make_uint2(pack2(s0 * p0, s1 * p1), pack2(s2 * p2, s3 * p3));
    *reinterpret_cast<uint2*>(&EA0[m * 64 + n0]) =
        make_uint2(pack2((1.0f - s0) * p0, (1.0f - s1) * p1),
                   pack2((1.0f - s2) * p2, (1.0f - s3) * p3));
  }
  #pragma unroll
  for (int k = 0; k < 4; ++k) {
    int i = tid + k * 256;
    int n = i >> 4, m0 = (i & 15) * 4;
    float pn = pa[n];
    float s0 = sig[m0][n], s1 = sig[m0 + 1][n];
    float s2 = sig[m0 + 2][n], s3 = sig[m0 + 3][n];
    *reinterpret_cast<uint2*>(&EB1[n * 64 + m0]) =
        make_uint2(pack2(s0 * pn, s1 * pn), pack2(s2 * pn, s3 * pn));
    *reinterpret_cast<uint2*>(&EB0[n * 64 + m0]) =
        make_uint2(pack2((1.0f - s0) * pn, (1.0f - s1) * pn),
                   pack2((1.0f - s2) * pn, (1.0f - s3) * pn));
  }
}

// ---------------- shared MFMA helpers (R5-validated byte patterns) ---------
static __device__ __forceinline__ void mm64(const short8 A[4][2],
                                            const short8 B[4][2],
                                            f32x16 C[2][2]) {
  #pragma unroll
  for (int ti = 0; ti < 2; ++ti)
    #pragma unroll
    for (int j = 0; j < 2; ++j)
      #pragma unroll
      for (int r = 0; r < 16; ++r) C[ti][j][r] = 0.0f;
  #pragma unroll
  for (int kc = 0; kc < 4; ++kc)
    #pragma unroll
    for (int j = 0; j < 2; ++j)
      #pragma unroll
      for (int ti = 0; ti < 2; ++ti)
        C[ti][j] = __builtin_amdgcn_mfma_f32_32x32x16_bf16(
            A[kc][ti], B[kc][j], C[ti][j], 0, 0, 0);
}

static __device__ __forceinline__ void loadA_g(short8 A[4][2],
                                               const unsigned short* M,
                                               int lo, int hi) {
  #pragma unroll
  for (int kc = 0; kc < 4; ++kc)
    #pragma unroll
    for (int ti = 0; ti < 2; ++ti)
      A[kc][ti] = *reinterpret_cast<const short8*>(
          &M[(32 * ti + lo) * 64 + 16 * kc + 8 * hi]);
}
static __device__ __forceinline__ void loadB_g(short8 B[4][2],
                                               const unsigned short* M,
                                               int lo, int hi) {
  #pragma unroll
  for (int kc = 0; kc < 4; ++kc)
    #pragma unroll
    for (int j = 0; j < 2; ++j)
      B[kc][j] = *reinterpret_cast<const short8*>(
          &M[(32 * j + lo) * 64 + 16 * kc + 8 * hi]);
}

// LDS role buffers, bf16, XOR-swizzled: byte ^= (row&7)<<4
static __device__ __forceinline__ void store_role(const f32x16 C[2][2],
                                                  char* base, int role,
                                                  int lo, int hi) {
  if (role == 0) {
    #pragma unroll
    for (int ti = 0; ti < 2; ++ti)
      #pragma unroll
      for (int j = 0; j < 2; ++j)
        #pragma unroll
        for (int r = 0; r < 16; ++r) {
          int m = 32 * ti + (r & 3) + 8 * (r >> 2) + 4 * hi;
          int n = 32 * j + lo;
          unsigned byteoff =
              ((unsigned)(m * 128 + n * 2)) ^ ((unsigned)(m & 7) << 4);
          *reinterpret_cast<unsigned short*>(base + byteoff) =
              bf16b(C[ti][j][r]);
        }
  } else {
    #pragma unroll
    for (int ti = 0; ti < 2; ++ti)
      #pragma unroll
      for (int j = 0; j < 2; ++j)
        #pragma unroll
        for (int rq = 0; rq < 4; ++rq) {
          int n = 32 * j + lo;
          int mb = 32 * ti + 8 * rq + 4 * hi;
          unsigned byteoff =
              ((unsigned)(n * 128 + mb * 2)) ^ ((unsigned)(n & 7) << 4);
          uint2 wv = make_uint2(
              pack2(C[ti][j][4 * rq + 0], C[ti][j][4 * rq + 1]),
              pack2(C[ti][j][4 * rq + 2], C[ti][j][4 * rq + 3]));
          *reinterpret_cast<uint2*>(base + byteoff) = wv;
        }
  }
}

static __device__ __forceinline__ void loadA_lds(short8 A[4][2],
                                                 const char* base,
                                                 int lo, int hi) {
  #pragma unroll
  for (int kc = 0; kc < 4; ++kc)
    #pragma unroll
    for (int ti = 0; ti < 2; ++ti) {
      int m = 32 * ti + lo;
      unsigned byteoff = ((unsigned)(m * 128 + (16 * kc + 8 * hi) * 2)) ^
                         ((unsigned)(m & 7) << 4);
      A[kc][ti] = *reinterpret_cast<const short8*>(base + byteoff);
    }
}
static __device__ __forceinline__ void loadB_lds(short8 B[4][2],
                                                 const char* base,
                                                 int lo, int hi) {
  #pragma unroll
  for (int kc = 0; kc < 4; ++kc)
    #pragma unroll
    for (int j = 0; j < 2; ++j) {
      int n = 32 * j + lo;
      unsigned byteoff = ((unsigned)(n * 128 + (16 * kc + 8 * hi) * 2)) ^
                         ((unsigned)(n & 7) << 4);
      B[kc][j] = *reinterpret_cast<const short8*>(base + byteoff);
    }
}

// C regs -> B-frags of the same matrix (validated lane^32 parity exchange)
static __device__ __forceinline__ void rebuildB(const f32x16 C[2][2],
                                                short8 B[4][2], int hi) {
  #pragma unroll
  for (int kc = 0; kc < 4; ++kc) {
    int Me = 2 * kc, Mo = 2 * kc + 1;
    int tie = Me >> 2, me = Me & 3;
    int tio = Mo >> 2, mo = Mo & 3;
    #pragma unroll
    for (int j = 0; j < 2; ++j) {
      unsigned pe0 = pack2(C[tie][j][4 * me + 0], C[tie][j][4 * me + 1]);
      unsigned pe1 = pack2(C[tie][j][4 * me + 2], C[tie][j][4 * me + 3]);
      unsigned po0 = pack2(C[tio][j][4 * mo + 0], C[tio][j][4 * mo + 1]);
      unsigned po1 = pack2(C[tio][j][4 * mo + 2], C[tio][j][4 * mo + 3]);
      unsigned s0 = hi ? pe0 : po0;
      unsigned s1 = hi ? pe1 : po1;
      unsigned r0 = (unsigned)__shfl_xor((int)s0, 32);
      unsigned r1 = (unsigned)__shfl_xor((int)s1, 32);
      U8 f;
      f.u[0] = hi ? r0 : pe0;
      f.u[1] = hi ? r1 : pe1;
      f.u[2] = hi ? po0 : r0;
      f.u[3] = hi ? po1 : r1;
      B[kc][j] = f.v;
    }
  }
}

// ---------------- quad_kernel: group products, depth-2 ----------------
__global__ __launch_bounds__(64) void quad_kernel(
    const unsigned short* __restrict__ EA, const unsigned short* __restrict__ EB,
    unsigned short* __restrict__ MqB) {
  __shared__ __align__(16) char Lsh[8192];

  int bid = blockIdx.x;
  int lane = threadIdx.x, lo = lane & 31, hi = lane >> 5;
  int v, nt, t0, g;
  if (bid < 240) { v = bid & 15; nt = 4; g = bid >> 4; t0 = 4 * g; }
  else           { v = bid - 240; nt = 3; g = 15; t0 = 60; }

  short8 A[4][2], B[4][2];
  f32x16 C1[2][2], C2[2][2], C3[2][2];

  if (nt == 4) {
    int b0 = v & 1, b1 = (v >> 1) & 1, b2 = (v >> 2) & 1, b3 = (v >> 3) & 1;
    // C1 = rightT = E3^T * E2^T
    loadA_g(A, EB + (size_t)((t0 + 3) * 2 + b3) * 4096, lo, hi);
    loadB_g(B, EA + (size_t)((t0 + 2) * 2 + b2) * 4096, lo, hi);
    mm64(A, B, C1);
    // C2 = leftT = E1^T * E0^T
    loadA_g(A, EB + (size_t)((t0 + 1) * 2 + b1) * 4096, lo, hi);
    loadB_g(B, EA + (size_t)((t0 + 0) * 2 + b0) * 4096, lo, hi);
    mm64(A, B, C2);
    // PT = rightT * leftT
    store_role(C1, Lsh, 0, lo, hi);      // single wave: ds ops program-ordered
    loadA_lds(A, Lsh, lo, hi);
    rebuildB(C2, B, hi);
    mm64(A, B, C3);
  } else {
    int b0 = v & 1, b1 = (v >> 1) & 1, b2 = (v >> 2) & 1;
    // C1 = E62^T * E61^T
    loadA_g(A, EB + (size_t)((t0 + 2) * 2 + b2) * 4096, lo, hi);
    loadB_g(B, EA + (size_t)((t0 + 1) * 2 + b1) * 4096, lo, hi);
    mm64(A, B, C1);
    // PT = C1 * E60^T
    store_role(C1, Lsh, 0, lo, hi);
    loadA_lds(A, Lsh, lo, hi);
    loadB_g(B, EA + (size_t)((t0 + 0) * 2 + b0) * 4096, lo, hi);
    mm64(A, B, C3);
  }

  // store PT with roles swapped: even g -> A-role(P) == role-1 pattern on PT;
  // odd g -> B-role(P) == role-0 pattern on PT.  (global, unswizzled)
  unsigned short* outp = MqB + (size_t)bid * 4096;
  if ((g & 1) == 0) {
    #pragma unroll
    for (int ti = 0; ti < 2; ++ti)
      #pragma unroll
      for (int j = 0; j < 2; ++j)
        #pragma unroll
        for (int rq = 0; rq < 4; ++rq) {
          int n = 32 * j + lo;
          int mb = 32 * ti + 8 * rq + 4 * hi;
          uint2 wv = make_uint2(
              pack2(C3[ti][j][4 * rq + 0], C3[ti][j][4 * rq + 1]),
              pack2(C3[ti][j][4 * rq + 2], C3[ti][j][4 * rq + 3]));
          *reinterpret_cast<uint2*>(&outp[n * 64 + mb]) = wv;
        }
  } else {
    #pragma unroll
    for (int ti = 0; ti < 2; ++ti)
      #pragma unroll
      for (int j = 0; j < 2; ++j)
        #pragma unroll
        for (int r = 0; r < 16; ++r) {
          int m = 32 * ti + (r & 3) + 8 * (r >> 2) + 4 * hi;
          int n = 32 * j + lo;
          outp[m * 64 + n] = bf16b(C3[ti][j][r]);
        }
  }
}

// ---------------- tree: 1 block/batch, 8 waves, depth-5 (R5, validated) ----
__global__ __launch_bounds__(512, 2) void tree_kernel(
    const float* __restrict__ x, const float* __restrict__ theta,
    const unsigned short* __restrict__ MqB, float* __restrict__ out) {
  __shared__ __align__(16) char Lsh[8 * 8192];

  int b = blockIdx.x, tid = threadIdx.x;
  int w = tid >> 6, lane = tid & 63, lo = lane & 31, hi = lane >> 5;

  unsigned long long mask = __ballot(x[b * 64 + lane] != 0.0f);

#define GIDX(g) ((g) < 15 ? (g) * 16 + (int)((mask >> (4 * (g))) & 15ull) \
                          : 240 + (int)((mask >> 60) & 7ull))

  short8 A[4][2], B[4][2];
  f32x16 C[2][2];

  // leaf: H_w = G_{2w} (A-role) x G_{2w+1} (B-role), from global
  {
    const unsigned short* GA = MqB + (size_t)GIDX(2 * w) * 4096;
    const unsigned short* GB = MqB + (size_t)GIDX(2 * w + 1) * 4096;
    loadA_g(A, GA, lo, hi);
    loadB_g(B, GB, lo, hi);
    mm64(A, B, C);
    store_role(C, Lsh + w * 8192, w & 1, lo, hi);
  }
  __syncthreads();

  if (w < 4)
    { loadA_lds(A, Lsh + (2 * w) * 8192, lo, hi);
      loadB_lds(B, Lsh + (2 * w + 1) * 8192, lo, hi); }
  __syncthreads();
  if (w < 4) {
    mm64(A, B, C);
    store_role(C, Lsh + w * 8192, w & 1, lo, hi);
  }
  __syncthreads();

  if (w < 2)
    { loadA_lds(A, Lsh + (2 * w) * 8192, lo, hi);
      loadB_lds(B, Lsh + (2 * w + 1) * 8192, lo, hi); }
  __syncthreads();
  if (w < 2) {
    mm64(A, B, C);
    store_role(C, Lsh + w * 8192, w & 1, lo, hi);
  }
  __syncthreads();

  if (w == 0) {
    loadA_lds(A, Lsh + 0, lo, hi);
    loadB_lds(B, Lsh + 8192, lo, hi);
    mm64(A, B, C);      // L = G_0 ... G_15 (fp32 regs)

    float* lf = reinterpret_cast<float*>(Lsh);
    #pragma unroll
    for (int ti = 0; ti < 2; ++ti)
      #pragma unroll
      for (int j = 0; j < 2; ++j)
        #pragma unroll
        for (int r = 0; r < 16; ++r) {
          int m = 32 * ti + (r & 3) + 8 * (r >> 2) + 4 * hi;
          int n = 32 * j + lo;
          lf[(n >> 2) * 256 + m * 4 + (n & 3)] = C[ti][j][r];
        }

    float th = theta[63 * 4096 + lane * 64];
    float sg = 1.0f / (1.0f + __expf(-th));
    float* u = lf + 4096;
    u[lane] = ((mask >> 63) & 1ull) ? sg : (1.0f - sg);

    const float4* Qm4 = reinterpret_cast<const float4*>(lf);
    float s0 = 0.f, s1 = 0.f, s2 = 0.f, s3 = 0.f;
    #pragma unroll
    for (int gq = 0; gq < 16; gq += 4) {
      float4 q0 = Qm4[(gq + 0) * 64 + lane];
      float4 q1 = Qm4[(gq + 1) * 64 + lane];
      float4 q2 = Qm4[(gq + 2) * 64 + lane];
      float4 q3 = Qm4[(gq + 3) * 64 + lane];
      float4 u0 = *(const float4*)&u[(gq + 0) * 4];
      float4 u1 = *(const float4*)&u[(gq + 1) * 4];
      float4 u2 = *(const float4*)&u[(gq + 2) * 4];
      float4 u3 = *(const float4*)&u[(gq + 3) * 4];
      s0 = fmaf(q0.x, u0.x, s0); s0 = fmaf(q0.y, u0.y, s0);
      s0 = fmaf(q0.z, u0.z, s0); s0 = fmaf(q0.w, u0.w, s0);
      s1 = fmaf(q1.x, u1.x, s1); s1 = fmaf(q1.y, u1.y, s1);
      s1 = fmaf(q1.z, u1.z, s1); s1 = fmaf(q1.w, u1.w, s1);
      s2 = fmaf(q2.x, u2.x, s2); s2 = fmaf(q2.y, u2.y, s2);
      s2 = fmaf(q2.z, u2.z, s2); s2 = fmaf(q2.w, u2.w, s2);
      s3 = fmaf(q3.x, u3.x, s3); s3 = fmaf(q3.y, u3.y, s3);
      s3 = fmaf(q3.z, u3.z, s3); s3 = fmaf(q3.w, u3.w, s3);
    }
    float s = (s0 + s1) + (s2 + s3);
    out[b * 64 + lane] = logf(s);
  }
#undef GIDX
}

extern "C" void kernel_launch(void* const* d_in, const int* in_sizes, int n_in,
                              void* d_out, int out_size, void* d_ws, size_t ws_size,
                              hipStream_t stream) {
  const float* x     = (const float*)d_in[0];  // (512, 64)
  const float* theta = (const float*)d_in[1];  // (1, 64, 64, 64)
  const float* ulpa  = (const float*)d_in[2];  // (1, 63, 1, 64)
  float* out = (float*)d_out;                  // (512, 64, 1)

  unsigned short* MqB = (unsigned short*)d_ws;            // 248*4096 bf16
  unsigned short* EA  = MqB + (size_t)248 * 4096;          // 63*2*4096 bf16
  unsigned short* EB  = EA + (size_t)NSTEP * 2 * 4096;     // 63*2*4096 bf16

  hipLaunchKernelGGL(e_kernel, dim3(NSTEP), dim3(256), 0, stream,
                     theta, ulpa, EA, EB);
  hipLaunchKernelGGL(quad_kernel, dim3(248), dim3(64), 0, stream,
                     EA, EB, MqB);
  hipLaunchKernelGGL(tree_kernel, dim3(512), dim3(512), 0, stream,
                     x, theta, MqB, out);
}

// Round 7
// 76.118 us; speedup vs baseline: 1.4186x; 1.1282x over previous
//
#include <hip/hip_runtime.h>
#include <hip/hip_bf16.h>

// BATCH=512, INPUT_SIZE=64, ALPHA_DIM=64
// out[b,:] = log( M_0 ... M_62 p ).  Pipeline:
//  e_kernel:    E[t][v] = sigma_v(theta_t) col-scaled by softmax(u_t), bf16,
//               dual layout EA (row-major) / EB (col-major). R6-validated.
//  quad_kernel: 248 group products (15 quads x 16 v + 8 triple v) via
//               depth-2 MFMA with transpose-operand aliasing (R6-validated);
//               stores PT directly in bf16 CHAIN layout:
//                 idx = (j>>3)*512 + a*8 + (j&7)   for P[a][j]
//               => lane a reads short8 at [g*512 + a*8] covering j=8g..8g+7.
//  chain_kernel: per batch, 16 matvec steps right-to-left with 3-buffer
//               2-step-ahead register prefetch. fp32 accum, one renorm.

#define NSTEP 63

typedef __attribute__((ext_vector_type(8)))  short short8;
typedef __attribute__((ext_vector_type(16))) float f32x16;

union U8 { short8 v; unsigned u[4]; unsigned short s[8]; };

static __device__ __forceinline__ unsigned short bf16b(float f) {
  union { __hip_bfloat16 h; unsigned short u; } cv;
  cv.h = __float2bfloat16(f);
  return cv.u;
}
static __device__ __forceinline__ unsigned pack2(float a, float b) {
  return (unsigned)bf16b(a) | ((unsigned)bf16b(b) << 16);
}
static __device__ __forceinline__ float bfcvt(unsigned short s) {
  return __uint_as_float((unsigned)s << 16);
}

// ---------------- e_kernel: E tables, dual layout (R6, validated) ----------
__global__ __launch_bounds__(256) void e_kernel(
    const float* __restrict__ theta, const float* __restrict__ ulpa,
    unsigned short* __restrict__ EA, unsigned short* __restrict__ EB) {
  int t = blockIdx.x;          // 0..62
  int tid = threadIdx.x;
  __shared__ float sig[64][65];
  __shared__ float pa[64];

  if (tid < 64) {
    float u = ulpa[t * 64 + tid];
    float m = u;
    #pragma unroll
    for (int o = 32; o >= 1; o >>= 1) m = fmaxf(m, __shfl_xor(m, o));
    float e = __expf(u - m);
    float s = e;
    #pragma unroll
    for (int o = 32; o >= 1; o >>= 1) s += __shfl_xor(s, o);
    pa[tid] = e / s;
  }

  const float4* th4 = (const float4*)(theta + t * 4096);
  #pragma unroll
  for (int k = 0; k < 4; ++k) {
    int i = tid + k * 256;
    float4 v = th4[i];
    int m = i >> 4, n0 = (i & 15) * 4;
    sig[m][n0 + 0] = 1.0f / (1.0f + __expf(-v.x));
    sig[m][n0 + 1] = 1.0f / (1.0f + __expf(-v.y));
    sig[m][n0 + 2] = 1.0f / (1.0f + __expf(-v.z));
    sig[m][n0 + 3] = 1.0f / (1.0f + __expf(-v.w));
  }
  __syncthreads();

  unsigned short* EA0 = EA + (size_t)(t * 2 + 0) * 4096;
  unsigned short* EA1 = EA + (size_t)(t * 2 + 1) * 4096;
  unsigned short* EB0 = EB + (size_t)(t * 2 + 0) * 4096;
  unsigned short* EB1 = EB + (size_t)(t * 2 + 1) * 4096;

  #pragma unroll
  for (int k = 0; k < 4; ++k) {
    int i = tid + k * 256;
    int m = i >> 4, n0 = (i & 15) * 4;
    float p0 = pa[n0], p1 = pa[n0 + 1], p2 = pa[n0 + 2], p3 = pa[n0 + 3];
    float s0 = sig[m][n0], s1 = sig[m][n0 + 1];
    float s2 = sig[m][n0 + 2], s3 = sig[m][n0 + 3];
    *reinterpret_cast<uint2*>(&EA1[m * 64 + n0]) =
        make_uint2(pack2(s0 * p0, s1 * p1), pack2(s2 * p2, s3 * p3));
    *reinterpret_cast<uint2*>(&EA0[m * 64 + n0]) =
        make_uint2(pack2((1.0f - s0) * p0, (1.0f - s1) * p1),
                   pack2((1.0f - s2) * p2, (1.0f - s3) * p3));
  }
  #pragma unroll
  for (int k = 0; k < 4; ++k) {
    int i = tid + k * 256;
    int n = i >> 4, m0 = (i & 15) * 4;
    float pn = pa[n];
    float s0 = sig[m0][n], s1 = sig[m0 + 1][n];
    float s2 = sig[m0 + 2][n], s3 = sig[m0 + 3][n];
    *reinterpret_cast<uint2*>(&EB1[n * 64 + m0]) =
        make_uint2(pack2(s0 * pn, s1 * pn), pack2(s2 * pn, s3 * pn));
    *reinterpret_cast<uint2*>(&EB0[n * 64 + m0]) =
        make_uint2(pack2((1.0f - s0) * pn, (1.0f - s1) * pn),
                   pack2((1.0f - s2) * pn, (1.0f - s3) * pn));
  }
}

// ---------------- shared MFMA helpers (R5/R6-validated) ----------------
static __device__ __forceinline__ void mm64(const short8 A[4][2],
                                            const short8 B[4][2],
                                            f32x16 C[2][2]) {
  #pragma unroll
  for (int ti = 0; ti < 2; ++ti)
    #pragma unroll
    for (int j = 0; j < 2; ++j)
      #pragma unroll
      for (int r = 0; r < 16; ++r) C[ti][j][r] = 0.0f;
  #pragma unroll
  for (int kc = 0; kc < 4; ++kc)
    #pragma unroll
    for (int j = 0; j < 2; ++j)
      #pragma unroll
      for (int ti = 0; ti < 2; ++ti)
        C[ti][j] = __builtin_amdgcn_mfma_f32_32x32x16_bf16(
            A[kc][ti], B[kc][j], C[ti][j], 0, 0, 0);
}

static __device__ __forceinline__ void loadA_g(short8 A[4][2],
                                               const unsigned short* M,
                                               int lo, int hi) {
  #pragma unroll
  for (int kc = 0; kc < 4; ++kc)
    #pragma unroll
    for (int ti = 0; ti < 2; ++ti)
      A[kc][ti] = *reinterpret_cast<const short8*>(
          &M[(32 * ti + lo) * 64 + 16 * kc + 8 * hi]);
}
static __device__ __forceinline__ void loadB_g(short8 B[4][2],
                                               const unsigned short* M,
                                               int lo, int hi) {
  #pragma unroll
  for (int kc = 0; kc < 4; ++kc)
    #pragma unroll
    for (int j = 0; j < 2; ++j)
      B[kc][j] = *reinterpret_cast<const short8*>(
          &M[(32 * j + lo) * 64 + 16 * kc + 8 * hi]);
}

// LDS role-0 buffer, bf16, XOR-swizzled: byte ^= (row&7)<<4
static __device__ __forceinline__ void store_role0(const f32x16 C[2][2],
                                                   char* base, int lo, int hi) {
  #pragma unroll
  for (int ti = 0; ti < 2; ++ti)
    #pragma unroll
    for (int j = 0; j < 2; ++j)
      #pragma unroll
      for (int r = 0; r < 16; ++r) {
        int m = 32 * ti + (r & 3) + 8 * (r >> 2) + 4 * hi;
        int n = 32 * j + lo;
        unsigned byteoff =
            ((unsigned)(m * 128 + n * 2)) ^ ((unsigned)(m & 7) << 4);
        *reinterpret_cast<unsigned short*>(base + byteoff) = bf16b(C[ti][j][r]);
      }
}

static __device__ __forceinline__ void loadA_lds(short8 A[4][2],
                                                 const char* base,
                                                 int lo, int hi) {
  #pragma unroll
  for (int kc = 0; kc < 4; ++kc)
    #pragma unroll
    for (int ti = 0; ti < 2; ++ti) {
      int m = 32 * ti + lo;
      unsigned byteoff = ((unsigned)(m * 128 + (16 * kc + 8 * hi) * 2)) ^
                         ((unsigned)(m & 7) << 4);
      A[kc][ti] = *reinterpret_cast<const short8*>(base + byteoff);
    }
}

// C regs -> B-frags of same matrix (validated lane^32 parity exchange)
static __device__ __forceinline__ void rebuildB(const f32x16 C[2][2],
                                                short8 B[4][2], int hi) {
  #pragma unroll
  for (int kc = 0; kc < 4; ++kc) {
    int Me = 2 * kc, Mo = 2 * kc + 1;
    int tie = Me >> 2, me = Me & 3;
    int tio = Mo >> 2, mo = Mo & 3;
    #pragma unroll
    for (int j = 0; j < 2; ++j) {
      unsigned pe0 = pack2(C[tie][j][4 * me + 0], C[tie][j][4 * me + 1]);
      unsigned pe1 = pack2(C[tie][j][4 * me + 2], C[tie][j][4 * me + 3]);
      unsigned po0 = pack2(C[tio][j][4 * mo + 0], C[tio][j][4 * mo + 1]);
      unsigned po1 = pack2(C[tio][j][4 * mo + 2], C[tio][j][4 * mo + 3]);
      unsigned s0 = hi ? pe0 : po0;
      unsigned s1 = hi ? pe1 : po1;
      unsigned r0 = (unsigned)__shfl_xor((int)s0, 32);
      unsigned r1 = (unsigned)__shfl_xor((int)s1, 32);
      U8 f;
      f.u[0] = hi ? r0 : pe0;
      f.u[1] = hi ? r1 : pe1;
      f.u[2] = hi ? po0 : r0;
      f.u[3] = hi ? po1 : r1;
      B[kc][j] = f.v;
    }
  }
}

// ---------------- quad_kernel: group products, depth-2 (R6) ----------------
// Output: PT stored straight into bf16 chain layout of P = product:
//   C3[m][n] = PT[m][n] = P[n][m]  =>  P[a=n][j=m] at (m>>3)*512 + n*8 + (m&7)
__global__ __launch_bounds__(64) void quad_kernel(
    const unsigned short* __restrict__ EA, const unsigned short* __restrict__ EB,
    unsigned short* __restrict__ MqC) {
  __shared__ __align__(16) char Lsh[8192];

  int bid = blockIdx.x;
  int lane = threadIdx.x, lo = lane & 31, hi = lane >> 5;
  int v, nt, t0;
  if (bid < 240) { v = bid & 15; nt = 4; t0 = 4 * (bid >> 4); }
  else           { v = bid - 240; nt = 3; t0 = 60; }

  short8 A[4][2], B[4][2];
  f32x16 C1[2][2], C2[2][2], C3[2][2];

  if (nt == 4) {
    int b0 = v & 1, b1 = (v >> 1) & 1, b2 = (v >> 2) & 1, b3 = (v >> 3) & 1;
    loadA_g(A, EB + (size_t)((t0 + 3) * 2 + b3) * 4096, lo, hi);  // E3^T
    loadB_g(B, EA + (size_t)((t0 + 2) * 2 + b2) * 4096, lo, hi);  // E2^T
    mm64(A, B, C1);                                               // (E2E3)^T
    loadA_g(A, EB + (size_t)((t0 + 1) * 2 + b1) * 4096, lo, hi);  // E1^T
    loadB_g(B, EA + (size_t)((t0 + 0) * 2 + b0) * 4096, lo, hi);  // E0^T
    mm64(A, B, C2);                                               // (E0E1)^T
    store_role0(C1, Lsh, lo, hi);   // single wave: ds ops program-ordered
    loadA_lds(A, Lsh, lo, hi);
    rebuildB(C2, B, hi);
    mm64(A, B, C3);                 // (E0E1E2E3)^T
  } else {
    int b0 = v & 1, b1 = (v >> 1) & 1, b2 = (v >> 2) & 1;
    loadA_g(A, EB + (size_t)((t0 + 2) * 2 + b2) * 4096, lo, hi);
    loadB_g(B, EA + (size_t)((t0 + 1) * 2 + b1) * 4096, lo, hi);
    mm64(A, B, C1);                                               // (E61E62)^T
    store_role0(C1, Lsh, lo, hi);
    loadA_lds(A, Lsh, lo, hi);
    loadB_g(B, EA + (size_t)((t0 + 0) * 2 + b0) * 4096, lo, hi);  // E60^T
    mm64(A, B, C3);                                               // (E60..E62)^T
  }

  unsigned short* outp = MqC + (size_t)bid * 4096;
  #pragma unroll
  for (int ti = 0; ti < 2; ++ti)
    #pragma unroll
    for (int j = 0; j < 2; ++j)
      #pragma unroll
      for (int r = 0; r < 16; ++r) {
        int m = 32 * ti + (r & 3) + 8 * (r >> 2) + 4 * hi;   // PT row = P col
        int n = 32 * j + lo;                                 // PT col = P row
        outp[(m >> 3) * 512 + n * 8 + (m & 7)] = bf16b(C3[ti][j][r]);
      }
}

// ---------------- chain: 16 matvec steps, 2-step-ahead prefetch ------------
__global__ __launch_bounds__(64) void chain_kernel(
    const float* __restrict__ x, const float* __restrict__ theta,
    const unsigned short* __restrict__ MqC, float* __restrict__ out) {
  int b = blockIdx.x;     // 0..511
  int lane = threadIdx.x; // 0..63

  unsigned long long mask = __ballot(x[b * 64 + lane] != 0.0f);

  __shared__ __align__(16) float u_lds[64];

  // u = p: sigma variant of theta[63][lane][0]  (R4-validated)
  float th = theta[63 * 4096 + lane * 64];
  float sg = 1.0f / (1.0f + __expf(-th));
  float u = ((mask >> 63) & 1ull) ? sg : (1.0f - sg);
  float acc = 0.0f;

#define GIDX(g) ((g) < 15 ? (g) * 16 + (int)((mask >> (4 * (g))) & 15ull) \
                          : 240 + (int)((mask >> 60) & 7ull))

  short8 qa[8], qb[8], qc[8];

#define PRE(REG, PG)                                                      \
  {                                                                       \
    const unsigned short* Pb = MqC + (size_t)GIDX(PG) * 4096 + lane * 8;  \
    _Pragma("unroll")                                                     \
    for (int gi = 0; gi < 8; ++gi)                                        \
      REG[gi] = *reinterpret_cast<const short8*>(Pb + gi * 512);          \
  }

  // One step: broadcast u via LDS (single wave: program-ordered ds + lgkmcnt
  // covers the write->read dep), prefetch group PG (2 ahead), 64 FMAs on 4
  // independent accumulators (chain depth 16).
#define STEP(QREG, PG, PREG)                                              \
  {                                                                       \
    u_lds[lane] = u;                                                      \
    if ((PG) >= 0) PRE(PREG, PG);                                         \
    float s0 = 0.f, s1 = 0.f, s2 = 0.f, s3 = 0.f;                         \
    _Pragma("unroll")                                                     \
    for (int gi = 0; gi < 8; ++gi) {                                      \
      U8 f; f.v = QREG[gi];                                               \
      float4 uu0 = *(const float4*)&u_lds[gi * 8];                        \
      float4 uu1 = *(const float4*)&u_lds[gi * 8 + 4];                    \
      s0 = fmaf(bfcvt(f.s[0]), uu0.x, s0);                                \
      s1 = fmaf(bfcvt(f.s[1]), uu0.y, s1);                                \
      s2 = fmaf(bfcvt(f.s[2]), uu0.z, s2);                                \
      s3 = fmaf(bfcvt(f.s[3]), uu0.w, s3);                                \
      s0 = fmaf(bfcvt(f.s[4]), uu1.x, s0);                                \
      s1 = fmaf(bfcvt(f.s[5]), uu1.y, s1);                                \
      s2 = fmaf(bfcvt(f.s[6]), uu1.z, s2);                                \
      s3 = fmaf(bfcvt(f.s[7]), uu1.w, s3);                                \
    }                                                                     \
    u = (s0 + s1) + (s2 + s3);                                            \
  }

  PRE(qa, 15);
  PRE(qb, 14);

  STEP(qa, 13, qc);   // g=15
  STEP(qb, 12, qa);   // g=14
  STEP(qc, 11, qb);   // g=13
  STEP(qa, 10, qc);   // g=12
  STEP(qb,  9, qa);   // g=11
  STEP(qc,  8, qb);   // g=10
  STEP(qa,  7, qc);   // g=9
  STEP(qb,  6, qa);   // g=8

  {  // renorm after 8 group-steps (R4-validated bound: values >> f32 floor)
    float m = u;
    #pragma unroll
    for (int o = 32; o >= 1; o >>= 1) m = fmaxf(m, __shfl_xor(m, o));
    acc += __logf(m);
    u *= (1.0f / m);
  }

  STEP(qc,  5, qb);   // g=7
  STEP(qa,  4, qc);   // g=6
  STEP(qb,  3, qa);   // g=5
  STEP(qc,  2, qb);   // g=4
  STEP(qa,  1, qc);   // g=3
  STEP(qb,  0, qa);   // g=2
  STEP(qc, -1, qb);   // g=1
  STEP(qa, -1, qb);   // g=0

#undef STEP
#undef PRE
#undef GIDX

  out[b * 64 + lane] = logf(u) + acc;
}

extern "C" void kernel_launch(void* const* d_in, const int* in_sizes, int n_in,
                              void* d_out, int out_size, void* d_ws, size_t ws_size,
                              hipStream_t stream) {
  const float* x     = (const float*)d_in[0];  // (512, 64)
  const float* theta = (const float*)d_in[1];  // (1, 64, 64, 64)
  const float* ulpa  = (const float*)d_in[2];  // (1, 63, 1, 64)
  float* out = (float*)d_out;                  // (512, 64, 1)

  unsigned short* MqC = (unsigned short*)d_ws;             // 248*4096 bf16
  unsigned short* EA  = MqC + (size_t)248 * 4096;          // 63*2*4096 bf16
  unsigned short* EB  = EA + (size_t)NSTEP * 2 * 4096;     // 63*2*4096 bf16

  hipLaunchKernelGGL(e_kernel, dim3(NSTEP), dim3(256), 0, stream,
                     theta, ulpa, EA, EB);
  hipLaunchKernelGGL(quad_kernel, dim3(248), dim3(64), 0, stream,
                     EA, EB, MqC);
  hipLaunchKernelGGL(chain_kernel, dim3(512), dim3(64), 0, stream,
                     x, theta, MqC, out);
}

// Round 8
// 73.895 us; speedup vs baseline: 1.4612x; 1.0301x over previous
//
#include <hip/hip_runtime.h>
#include <hip/hip_bf16.h>

// BATCH=512, INPUT_SIZE=64, ALPHA_DIM=64
// out[b,:] = log( M_0 ... M_62 p ).  Pipeline:
//  e_kernel:    E[t][v] bf16 dual layout (R6-validated, unchanged).
//  quad_kernel: 248 group products -> bf16 chain layout (R7-validated,
//               unchanged):  P[a][j] at (j>>3)*512 + a*8 + (j&7).
//  chain_kernel (NEW): 1 block/batch, 4 waves. Each matvec step is split
//               across waves: lane (w,l) owns row a=16w+(l&15), j-quarter
//               q=l>>4 (16 j's); 16-FMA partial + shfl_xor(16,32) fold;
//               ping-pong u in LDS, one barrier/step. 2-step-ahead register
//               prefetch of the 2 table frags per lane.

#define NSTEP 63

typedef __attribute__((ext_vector_type(8)))  short short8;
typedef __attribute__((ext_vector_type(16))) float f32x16;

union U8 { short8 v; unsigned u[4]; unsigned short s[8]; };

static __device__ __forceinline__ unsigned short bf16b(float f) {
  union { __hip_bfloat16 h; unsigned short u; } cv;
  cv.h = __float2bfloat16(f);
  return cv.u;
}
static __device__ __forceinline__ unsigned pack2(float a, float b) {
  return (unsigned)bf16b(a) | ((unsigned)bf16b(b) << 16);
}
static __device__ __forceinline__ float bfcvt(unsigned short s) {
  return __uint_as_float((unsigned)s << 16);
}

// ---------------- e_kernel: E tables, dual layout (R6, validated) ----------
__global__ __launch_bounds__(256) void e_kernel(
    const float* __restrict__ theta, const float* __restrict__ ulpa,
    unsigned short* __restrict__ EA, unsigned short* __restrict__ EB) {
  int t = blockIdx.x;          // 0..62
  int tid = threadIdx.x;
  __shared__ float sig[64][65];
  __shared__ float pa[64];

  if (tid < 64) {
    float u = ulpa[t * 64 + tid];
    float m = u;
    #pragma unroll
    for (int o = 32; o >= 1; o >>= 1) m = fmaxf(m, __shfl_xor(m, o));
    float e = __expf(u - m);
    float s = e;
    #pragma unroll
    for (int o = 32; o >= 1; o >>= 1) s += __shfl_xor(s, o);
    pa[tid] = e / s;
  }

  const float4* th4 = (const float4*)(theta + t * 4096);
  #pragma unroll
  for (int k = 0; k < 4; ++k) {
    int i = tid + k * 256;
    float4 v = th4[i];
    int m = i >> 4, n0 = (i & 15) * 4;
    sig[m][n0 + 0] = 1.0f / (1.0f + __expf(-v.x));
    sig[m][n0 + 1] = 1.0f / (1.0f + __expf(-v.y));
    sig[m][n0 + 2] = 1.0f / (1.0f + __expf(-v.z));
    sig[m][n0 + 3] = 1.0f / (1.0f + __expf(-v.w));
  }
  __syncthreads();

  unsigned short* EA0 = EA + (size_t)(t * 2 + 0) * 4096;
  unsigned short* EA1 = EA + (size_t)(t * 2 + 1) * 4096;
  unsigned short* EB0 = EB + (size_t)(t * 2 + 0) * 4096;
  unsigned short* EB1 = EB + (size_t)(t * 2 + 1) * 4096;

  #pragma unroll
  for (int k = 0; k < 4; ++k) {
    int i = tid + k * 256;
    int m = i >> 4, n0 = (i & 15) * 4;
    float p0 = pa[n0], p1 = pa[n0 + 1], p2 = pa[n0 + 2], p3 = pa[n0 + 3];
    float s0 = sig[m][n0], s1 = sig[m][n0 + 1];
    float s2 = sig[m][n0 + 2], s3 = sig[m][n0 + 3];
    *reinterpret_cast<uint2*>(&EA1[m * 64 + n0]) =
        make_uint2(pack2(s0 * p0, s1 * p1), pack2(s2 * p2, s3 * p3));
    *reinterpret_cast<uint2*>(&EA0[m * 64 + n0]) =
        make_uint2(pack2((1.0f - s0) * p0, (1.0f - s1) * p1),
                   pack2((1.0f - s2) * p2, (1.0f - s3) * p3));
  }
  #pragma unroll
  for (int k = 0; k < 4; ++k) {
    int i = tid + k * 256;
    int n = i >> 4, m0 = (i & 15) * 4;
    float pn = pa[n];
    float s0 = sig[m0][n], s1 = sig[m0 + 1][n];
    float s2 = sig[m0 + 2][n], s3 = sig[m0 + 3][n];
    *reinterpret_cast<uint2*>(&EB1[n * 64 + m0]) =
        make_uint2(pack2(s0 * pn, s1 * pn), pack2(s2 * pn, s3 * pn));
    *reinterpret_cast<uint2*>(&EB0[n * 64 + m0]) =
        make_uint2(pack2((1.0f - s0) * pn, (1.0f - s1) * pn),
                   pack2((1.0f - s2) * pn, (1.0f - s3) * pn));
  }
}

// ---------------- shared MFMA helpers (R5/R6-validated) ----------------
static __device__ __forceinline__ void mm64(const short8 A[4][2],
                                            const short8 B[4][2],
                                            f32x16 C[2][2]) {
  #pragma unroll
  for (int ti = 0; ti < 2; ++ti)
    #pragma unroll
    for (int j = 0; j < 2; ++j)
      #pragma unroll
      for (int r = 0; r < 16; ++r) C[ti][j][r] = 0.0f;
  #pragma unroll
  for (int kc = 0; kc < 4; ++kc)
    #pragma unroll
    for (int j = 0; j < 2; ++j)
      #pragma unroll
      for (int ti = 0; ti < 2; ++ti)
        C[ti][j] = __builtin_amdgcn_mfma_f32_32x32x16_bf16(
            A[kc][ti], B[kc][j], C[ti][j], 0, 0, 0);
}

static __device__ __forceinline__ void loadA_g(short8 A[4][2],
                                               const unsigned short* M,
                                               int lo, int hi) {
  #pragma unroll
  for (int kc = 0; kc < 4; ++kc)
    #pragma unroll
    for (int ti = 0; ti < 2; ++ti)
      A[kc][ti] = *reinterpret_cast<const short8*>(
          &M[(32 * ti + lo) * 64 + 16 * kc + 8 * hi]);
}
static __device__ __forceinline__ void loadB_g(short8 B[4][2],
                                               const unsigned short* M,
                                               int lo, int hi) {
  #pragma unroll
  for (int kc = 0; kc < 4; ++kc)
    #pragma unroll
    for (int j = 0; j < 2; ++j)
      B[kc][j] = *reinterpret_cast<const short8*>(
          &M[(32 * j + lo) * 64 + 16 * kc + 8 * hi]);
}

// LDS role-0 buffer, bf16, XOR-swizzled: byte ^= (row&7)<<4
static __device__ __forceinline__ void store_role0(const f32x16 C[2][2],
                                                   char* base, int lo, int hi) {
  #pragma unroll
  for (int ti = 0; ti < 2; ++ti)
    #pragma unroll
    for (int j = 0; j < 2; ++j)
      #pragma unroll
      for (int r = 0; r < 16; ++r) {
        int m = 32 * ti + (r & 3) + 8 * (r >> 2) + 4 * hi;
        int n = 32 * j + lo;
        unsigned byteoff =
            ((unsigned)(m * 128 + n * 2)) ^ ((unsigned)(m & 7) << 4);
        *reinterpret_cast<unsigned short*>(base + byteoff) = bf16b(C[ti][j][r]);
      }
}

static __device__ __forceinline__ void loadA_lds(short8 A[4][2],
                                                 const char* base,
                                                 int lo, int hi) {
  #pragma unroll
  for (int kc = 0; kc < 4; ++kc)
    #pragma unroll
    for (int ti = 0; ti < 2; ++ti) {
      int m = 32 * ti + lo;
      unsigned byteoff = ((unsigned)(m * 128 + (16 * kc + 8 * hi) * 2)) ^
                         ((unsigned)(m & 7) << 4);
      A[kc][ti] = *reinterpret_cast<const short8*>(base + byteoff);
    }
}

// C regs -> B-frags of same matrix (validated lane^32 parity exchange)
static __device__ __forceinline__ void rebuildB(const f32x16 C[2][2],
                                                short8 B[4][2], int hi) {
  #pragma unroll
  for (int kc = 0; kc < 4; ++kc) {
    int Me = 2 * kc, Mo = 2 * kc + 1;
    int tie = Me >> 2, me = Me & 3;
    int tio = Mo >> 2, mo = Mo & 3;
    #pragma unroll
    for (int j = 0; j < 2; ++j) {
      unsigned pe0 = pack2(C[tie][j][4 * me + 0], C[tie][j][4 * me + 1]);
      unsigned pe1 = pack2(C[tie][j][4 * me + 2], C[tie][j][4 * me + 3]);
      unsigned po0 = pack2(C[tio][j][4 * mo + 0], C[tio][j][4 * mo + 1]);
      unsigned po1 = pack2(C[tio][j][4 * mo + 2], C[tio][j][4 * mo + 3]);
      unsigned s0 = hi ? pe0 : po0;
      unsigned s1 = hi ? pe1 : po1;
      unsigned r0 = (unsigned)__shfl_xor((int)s0, 32);
      unsigned r1 = (unsigned)__shfl_xor((int)s1, 32);
      U8 f;
      f.u[0] = hi ? r0 : pe0;
      f.u[1] = hi ? r1 : pe1;
      f.u[2] = hi ? po0 : r0;
      f.u[3] = hi ? po1 : r1;
      B[kc][j] = f.v;
    }
  }
}

// ---------------- quad_kernel: group products, depth-2 (R7, validated) -----
__global__ __launch_bounds__(64) void quad_kernel(
    const unsigned short* __restrict__ EA, const unsigned short* __restrict__ EB,
    unsigned short* __restrict__ MqC) {
  __shared__ __align__(16) char Lsh[8192];

  int bid = blockIdx.x;
  int lane = threadIdx.x, lo = lane & 31, hi = lane >> 5;
  int v, nt, t0;
  if (bid < 240) { v = bid & 15; nt = 4; t0 = 4 * (bid >> 4); }
  else           { v = bid - 240; nt = 3; t0 = 60; }

  short8 A[4][2], B[4][2];
  f32x16 C1[2][2], C2[2][2], C3[2][2];

  if (nt == 4) {
    int b0 = v & 1, b1 = (v >> 1) & 1, b2 = (v >> 2) & 1, b3 = (v >> 3) & 1;
    loadA_g(A, EB + (size_t)((t0 + 3) * 2 + b3) * 4096, lo, hi);  // E3^T
    loadB_g(B, EA + (size_t)((t0 + 2) * 2 + b2) * 4096, lo, hi);  // E2^T
    mm64(A, B, C1);                                               // (E2E3)^T
    loadA_g(A, EB + (size_t)((t0 + 1) * 2 + b1) * 4096, lo, hi);  // E1^T
    loadB_g(B, EA + (size_t)((t0 + 0) * 2 + b0) * 4096, lo, hi);  // E0^T
    mm64(A, B, C2);                                               // (E0E1)^T
    store_role0(C1, Lsh, lo, hi);   // single wave: ds ops program-ordered
    loadA_lds(A, Lsh, lo, hi);
    rebuildB(C2, B, hi);
    mm64(A, B, C3);                 // (E0E1E2E3)^T
  } else {
    int b0 = v & 1, b1 = (v >> 1) & 1, b2 = (v >> 2) & 1;
    loadA_g(A, EB + (size_t)((t0 + 2) * 2 + b2) * 4096, lo, hi);
    loadB_g(B, EA + (size_t)((t0 + 1) * 2 + b1) * 4096, lo, hi);
    mm64(A, B, C1);                                               // (E61E62)^T
    store_role0(C1, Lsh, lo, hi);
    loadA_lds(A, Lsh, lo, hi);
    loadB_g(B, EA + (size_t)((t0 + 0) * 2 + b0) * 4096, lo, hi);  // E60^T
    mm64(A, B, C3);                                               // (E60..E62)^T
  }

  unsigned short* outp = MqC + (size_t)bid * 4096;
  #pragma unroll
  for (int ti = 0; ti < 2; ++ti)
    #pragma unroll
    for (int j = 0; j < 2; ++j)
      #pragma unroll
      for (int r = 0; r < 16; ++r) {
        int m = 32 * ti + (r & 3) + 8 * (r >> 2) + 4 * hi;   // PT row = P col
        int n = 32 * j + lo;                                 // PT col = P row
        outp[(m >> 3) * 512 + n * 8 + (m & 7)] = bf16b(C3[ti][j][r]);
      }
}

// ---------------- chain: 16 steps, 4 waves/batch, split matvec -------------
__global__ __launch_bounds__(256) void chain_kernel(
    const float* __restrict__ x, const float* __restrict__ theta,
    const unsigned short* __restrict__ MqC, float* __restrict__ out) {
  int b = blockIdx.x;           // 0..511
  int tid = threadIdx.x;
  int w = tid >> 6, l = tid & 63;
  int al = l & 15;              // local row
  int q = l >> 4;               // j-quarter: j in [16q, 16q+16)
  int a = 16 * w + al;          // output row owned by this lane

  // each wave independently computes the same 64-bit mask
  unsigned long long mask = __ballot(x[b * 64 + l] != 0.0f);

  __shared__ __align__(16) float ubuf[2][64];

  // init u = p (sigma variant of theta[63][l][0]); wave 0 writes buf 0
  float th = theta[63 * 4096 + l * 64];
  float sg = 1.0f / (1.0f + __expf(-th));
  float pv = ((mask >> 63) & 1ull) ? sg : (1.0f - sg);
  if (w == 0) ubuf[0][l] = pv;
  __syncthreads();

#define GIDX(g) ((g) < 15 ? (g) * 16 + (int)((mask >> (4 * (g))) & 15ull) \
                          : 240 + (int)((mask >> 60) & 7ull))

  // per-lane table frags: P[a][16q+e] (frag0) and P[a][16q+8+e] (frag1)
  short8 qa[2], qb[2], qc[2];

#define PRE(REG, PG)                                                        \
  {                                                                         \
    const unsigned short* Pb =                                              \
        MqC + (size_t)GIDX(PG) * 4096 + (q * 1024 + a * 8);                 \
    REG[0] = *reinterpret_cast<const short8*>(Pb);                          \
    REG[1] = *reinterpret_cast<const short8*>(Pb + 512);                    \
  }

  float rscale = 1.0f, acc = 0.0f;

  // One step: read u quarter (broadcast within 16-lane group), 16 FMAs,
  // fold partials across q via shfl_xor(16,32), q==0 lanes write u_new to
  // the other buffer, barrier.  LAST: write out directly, no barrier.
#define STEP(QREG, PG, PREG, CUR, DO_RS, LAST)                              \
  {                                                                         \
    if ((PG) >= 0) PRE(PREG, PG);                                           \
    const float* uc = ubuf[CUR];                                            \
    float4 u0 = *(const float4*)&uc[16 * q + 0];                            \
    float4 u1 = *(const float4*)&uc[16 * q + 4];                            \
    float4 u2 = *(const float4*)&uc[16 * q + 8];                            \
    float4 u3 = *(const float4*)&uc[16 * q + 12];                           \
    U8 f0, f1;                                                              \
    f0.v = QREG[0]; f1.v = QREG[1];                                         \
    float s0 = 0.f, s1 = 0.f, s2 = 0.f, s3 = 0.f;                           \
    s0 = fmaf(bfcvt(f0.s[0]), u0.x, s0);                                    \
    s1 = fmaf(bfcvt(f0.s[1]), u0.y, s1);                                    \
    s2 = fmaf(bfcvt(f0.s[2]), u0.z, s2);                                    \
    s3 = fmaf(bfcvt(f0.s[3]), u0.w, s3);                                    \
    s0 = fmaf(bfcvt(f0.s[4]), u1.x, s0);                                    \
    s1 = fmaf(bfcvt(f0.s[5]), u1.y, s1);                                    \
    s2 = fmaf(bfcvt(f0.s[6]), u1.z, s2);                                    \
    s3 = fmaf(bfcvt(f0.s[7]), u1.w, s3);                                    \
    s0 = fmaf(bfcvt(f1.s[0]), u2.x, s0);                                    \
    s1 = fmaf(bfcvt(f1.s[1]), u2.y, s1);                                    \
    s2 = fmaf(bfcvt(f1.s[2]), u2.z, s2);                                    \
    s3 = fmaf(bfcvt(f1.s[3]), u2.w, s3);                                    \
    s0 = fmaf(bfcvt(f1.s[4]), u3.x, s0);                                    \
    s1 = fmaf(bfcvt(f1.s[5]), u3.y, s1);                                    \
    s2 = fmaf(bfcvt(f1.s[6]), u3.z, s2);                                    \
    s3 = fmaf(bfcvt(f1.s[7]), u3.w, s3);                                    \
    float s = (s0 + s1) + (s2 + s3);                                        \
    s += __shfl_xor(s, 16);                                                 \
    s += __shfl_xor(s, 32);                                                 \
    if (DO_RS) s *= rscale;                                                 \
    if (LAST) {                                                             \
      if (q == 0) out[b * 64 + a] = logf(s) + acc;                          \
    } else {                                                                \
      if (q == 0) ubuf[(CUR) ^ 1][a] = s;                                   \
      __syncthreads();                                                      \
    }                                                                       \
  }

  PRE(qa, 15);
  PRE(qb, 14);

  STEP(qa, 13, qc, 0, 0, 0);   // g=15
  STEP(qb, 12, qa, 1, 0, 0);   // g=14
  STEP(qc, 11, qb, 0, 0, 0);   // g=13
  STEP(qa, 10, qc, 1, 0, 0);   // g=12
  STEP(qb,  9, qa, 0, 0, 0);   // g=11
  STEP(qc,  8, qb, 1, 0, 0);   // g=10
  STEP(qa,  7, qc, 0, 0, 0);   // g=9
  STEP(qb,  6, qa, 1, 0, 0);   // g=8  -> u in ubuf[0]

  {  // renorm (same placement as R7: after 8 group-steps = 32 t's)
    float uv = ubuf[0][l];
    float m = uv;
    #pragma unroll
    for (int o = 32; o >= 1; o >>= 1) m = fmaxf(m, __shfl_xor(m, o));
    rscale = 1.0f / m;
    acc = __logf(m);
    // reads only; ubuf[0] was written+barriered, next step reads it again
  }

  STEP(qc,  5, qb, 0, 1, 0);   // g=7, applies rscale
  STEP(qa,  4, qc, 1, 0, 0);   // g=6
  STEP(qb,  3, qa, 0, 0, 0);   // g=5
  STEP(qc,  2, qb, 1, 0, 0);   // g=4
  STEP(qa,  1, qc, 0, 0, 0);   // g=3
  STEP(qb,  0, qa, 1, 0, 0);   // g=2
  STEP(qc, -1, qb, 0, 0, 0);   // g=1
  STEP(qa, -1, qb, 1, 0, 1);   // g=0, write out

#undef STEP
#undef PRE
#undef GIDX
}

extern "C" void kernel_launch(void* const* d_in, const int* in_sizes, int n_in,
                              void* d_out, int out_size, void* d_ws, size_t ws_size,
                              hipStream_t stream) {
  const float* x     = (const float*)d_in[0];  // (512, 64)
  const float* theta = (const float*)d_in[1];  // (1, 64, 64, 64)
  const float* ulpa  = (const float*)d_in[2];  // (1, 63, 1, 64)
  float* out = (float*)d_out;                  // (512, 64, 1)

  unsigned short* MqC = (unsigned short*)d_ws;             // 248*4096 bf16
  unsigned short* EA  = MqC + (size_t)248 * 4096;          // 63*2*4096 bf16
  unsigned short* EB  = EA + (size_t)NSTEP * 2 * 4096;     // 63*2*4096 bf16

  hipLaunchKernelGGL(e_kernel, dim3(NSTEP), dim3(256), 0, stream,
                     theta, ulpa, EA, EB);
  hipLaunchKernelGGL(quad_kernel, dim3(248), dim3(64), 0, stream,
                     EA, EB, MqC);
  hipLaunchKernelGGL(chain_kernel, dim3(512), dim3(256), 0, stream,
                     x, theta, MqC, out);
}